// Round 8
// baseline (286.764 us; speedup 1.0000x reference)
//
#include <hip/hip_runtime.h>
#include <hip/hip_bf16.h>
#include <math.h>

#define SEQ   2048
#define BATCH 2
#define NROWS 4096      /* BATCH*SEQ */
#define DIMM  1024
#define QKV3  3072
#define FFD   4096
#define NHEAD 16
#define DHEAD 64

typedef __bf16 bf16;
typedef __bf16 bf16x4 __attribute__((ext_vector_type(4)));
typedef __bf16 bf16x8 __attribute__((ext_vector_type(8)));
typedef float  f32x4  __attribute__((ext_vector_type(4)));

static __device__ __forceinline__ f32x4 mfma16(bf16x8 a, bf16x8 b, f32x4 c) {
    return __builtin_amdgcn_mfma_f32_16x16x32_bf16(a, b, c, 0, 0, 0);
}

#define GLDS16(gp, lp) __builtin_amdgcn_global_load_lds( \
    (__attribute__((address_space(1))) void*)(gp),       \
    (__attribute__((address_space(3))) void*)(lp), 16, 0, 0)

// ---------------------------------------------------------------------------
// Transpose + cast: src fp32 [K][N] -> dst bf16 [N][K]
// ---------------------------------------------------------------------------
__global__ __launch_bounds__(256) void tcast_kernel(
    const float* __restrict__ src, bf16* __restrict__ dst, int K, int N)
{
    __shared__ float tile[32][33];
    const int n0 = blockIdx.x * 32;
    const int k0 = blockIdx.y * 32;
    const int r = threadIdx.x >> 5;   // 0..7
    const int c = threadIdx.x & 31;
    #pragma unroll
    for (int i = 0; i < 4; ++i)
        tile[r + 8 * i][c] = src[(size_t)(k0 + r + 8 * i) * N + n0 + c];
    __syncthreads();
    #pragma unroll
    for (int i = 0; i < 4; ++i)
        dst[(size_t)(n0 + r + 8 * i) * K + k0 + c] = (bf16)tile[c][r + 8 * i];
}

// ---------------------------------------------------------------------------
// LayerNorm fp32 [NROWS][1024] -> bf16, one block per row
// ---------------------------------------------------------------------------
__global__ __launch_bounds__(256) void ln_cast_kernel(
    const float* __restrict__ x, const float* __restrict__ g,
    const float* __restrict__ b, bf16* __restrict__ out)
{
    const int row = blockIdx.x;
    const int t = threadIdx.x;
    const float4 v = ((const float4*)(x + (size_t)row * DIMM))[t];
    float s  = v.x + v.y + v.z + v.w;
    float sq = v.x * v.x + v.y * v.y + v.z * v.z + v.w * v.w;
    #pragma unroll
    for (int m = 1; m < 64; m <<= 1) {
        s  += __shfl_xor(s, m, 64);
        sq += __shfl_xor(sq, m, 64);
    }
    __shared__ float ss[4], ssq[4];
    const int wave = t >> 6;
    if ((t & 63) == 0) { ss[wave] = s; ssq[wave] = sq; }
    __syncthreads();
    s  = ss[0] + ss[1] + ss[2] + ss[3];
    sq = ssq[0] + ssq[1] + ssq[2] + ssq[3];
    const float mean = s * (1.0f / DIMM);
    const float var  = sq * (1.0f / DIMM) - mean * mean;
    const float rs   = rsqrtf(var + 1e-5f);
    const float4 gv = ((const float4*)g)[t];
    const float4 bv = ((const float4*)b)[t];
    bf16* o = out + (size_t)row * DIMM + t * 4;
    o[0] = (bf16)((v.x - mean) * rs * gv.x + bv.x);
    o[1] = (bf16)((v.y - mean) * rs * gv.y + bv.y);
    o[2] = (bf16)((v.z - mean) * rs * gv.z + bv.z);
    o[3] = (bf16)((v.w - mean) * rs * gv.w + bv.w);
}

// ---------------------------------------------------------------------------
// bf16 MFMA GEMM, double-buffered (T3 2-phase): one __syncthreads per K-step;
// STAGE(next) issued fire-and-forget right after the barrier so the loads get
// the whole compute phase (16 MFMA + 8 ds_read) to land (attn-proven pattern).
// C[M][N] = A[M][K] @ B[K][N], B given as BT[N][K], row stride ld.
// 128x128 tile, BK=32, 4 waves, 4x4 16x16x32 frags. XCD-chunk swizzle (T1).
// EPI: 0 = bf16 out; 1 = +bias +residual, fp32 out; 2 = +bias, GELU, bf16 out
//      3 = split-K partial: ks = idx / tiles; fp32 partial to (ks==0 ? Cout
//          : res-as-C2); A/BT advanced by ks*K columns.
// ---------------------------------------------------------------------------
template<int EPI>
__global__ __launch_bounds__(256, 4)
void gemm_bt_kernel(const bf16* __restrict__ A, const bf16* __restrict__ BT,
                    const float* __restrict__ bias, const float* __restrict__ res,
                    void* __restrict__ Cout, int M, int N, int K, int ld)
{
    __shared__ bf16 As[2][4096];   // [buf][128 m][32 k]
    __shared__ bf16 Bs[2][4096];
    const int nb = N >> 7;
    const int chunk = (int)gridDim.x >> 3;
    int idx = (blockIdx.x & 7) * chunk + (blockIdx.x >> 3);
    int ks = 0;
    if (EPI == 3) {
        const int tiles = (M >> 7) * nb;
        ks = idx / tiles;
        idx -= ks * tiles;
    }
    const int bm = idx / nb, bn = idx - bm * nb;
    const int tm = bm << 7, tn = bn << 7;
    const int tid = threadIdx.x;
    const int lane = tid & 63, wave = tid >> 6;
    const int wm = (wave >> 1) << 6, wn = (wave & 1) << 6;
    const int kofs = ks * K;   // column offset for split-K slice

    const bf16* ga = A  + (size_t)(tm + wave * 32 + (lane >> 2)) * ld + kofs + ((lane & 3) << 3);
    const bf16* gb = BT + (size_t)(tn + wave * 32 + (lane >> 2)) * ld + kofs + ((lane & 3) << 3);
    const size_t k16 = (size_t)16 * ld;

    f32x4 acc[4][4] = {};
    const int ro = (lane & 15) * 32 + ((lane >> 4) << 3);

#define GSTAGE(BUF, KO) do {                          \
        bf16* la_ = &As[BUF][wave * 1024];            \
        bf16* lb_ = &Bs[BUF][wave * 1024];            \
        GLDS16(ga + (KO),       la_);                 \
        GLDS16(ga + (KO) + k16, la_ + 512);           \
        GLDS16(gb + (KO),       lb_);                 \
        GLDS16(gb + (KO) + k16, lb_ + 512);           \
    } while (0)

    GSTAGE(0, 0);
    int cur = 0;
    for (int k0 = 0; k0 < K; k0 += 32) {
        __syncthreads();   // drains vmcnt(0): STAGE(k0) resident; buf cur^1 free
        if (k0 + 32 < K) GSTAGE(cur ^ 1, k0 + 32);   // fire-and-forget
        bf16x8 af[4], bfr[4];
        #pragma unroll
        for (int i = 0; i < 4; ++i) {
            af[i]  = *(const bf16x8*)(&As[cur][0] + (wm + i * 16) * 32 + ro);
            bfr[i] = *(const bf16x8*)(&Bs[cur][0] + (wn + i * 16) * 32 + ro);
        }
        #pragma unroll
        for (int i = 0; i < 4; ++i)
            #pragma unroll
            for (int j = 0; j < 4; ++j)
                acc[i][j] = mfma16(af[i], bfr[j], acc[i][j]);
        cur ^= 1;
    }
#undef GSTAGE

    const int r0 = tm + wm + ((lane >> 4) << 2);
    const int c0 = tn + wn + (lane & 15);
    if (EPI == 0) {
        bf16* C = (bf16*)Cout;
        #pragma unroll
        for (int i = 0; i < 4; ++i)
            #pragma unroll
            for (int j = 0; j < 4; ++j)
                #pragma unroll
                for (int r = 0; r < 4; ++r)
                    C[(size_t)(r0 + i * 16 + r) * N + (c0 + j * 16)] = (bf16)acc[i][j][r];
    } else if (EPI == 1) {
        float* C = (float*)Cout;
        #pragma unroll
        for (int j = 0; j < 4; ++j) {
            const float bv = bias[c0 + j * 16];
            #pragma unroll
            for (int i = 0; i < 4; ++i)
                #pragma unroll
                for (int r = 0; r < 4; ++r) {
                    const size_t idx2 = (size_t)(r0 + i * 16 + r) * N + (c0 + j * 16);
                    C[idx2] = acc[i][j][r] + bv + res[idx2];
                }
        }
    } else if (EPI == 2) {
        bf16* C = (bf16*)Cout;
        #pragma unroll
        for (int j = 0; j < 4; ++j) {
            const float bv = bias[c0 + j * 16];
            #pragma unroll
            for (int i = 0; i < 4; ++i)
                #pragma unroll
                for (int r = 0; r < 4; ++r) {
                    const float v = acc[i][j][r] + bv;
                    const float gl = 0.5f * v * (1.0f + erff(v * 0.70710678118654752f));
                    C[(size_t)(r0 + i * 16 + r) * N + (c0 + j * 16)] = (bf16)gl;
                }
        }
    } else {   // EPI == 3: fp32 partial, slice ks
        float* C = (float*)(ks == 0 ? Cout : (void*)res);
        #pragma unroll
        for (int j = 0; j < 4; ++j)
            #pragma unroll
            for (int i = 0; i < 4; ++i)
                #pragma unroll
                for (int r = 0; r < 4; ++r)
                    C[(size_t)(r0 + i * 16 + r) * N + (c0 + j * 16)] = acc[i][j][r];
    }
}

// ---------------------------------------------------------------------------
// FF2 split-K reduce: out = p0 + p1 + bias + res  (all fp32, [NROWS][DIMM])
// ---------------------------------------------------------------------------
__global__ __launch_bounds__(256) void ff2_reduce_kernel(
    const float* __restrict__ p0, const float* __restrict__ p1,
    const float* __restrict__ bias, const float* __restrict__ res,
    float* __restrict__ out)
{
    const int i = blockIdx.x * 256 + threadIdx.x;    // float4 index
    const float4 a = ((const float4*)p0)[i];
    const float4 b = ((const float4*)p1)[i];
    const float4 r = ((const float4*)res)[i];
    const float4 g = ((const float4*)bias)[i & 255]; // DIMM/4 = 256 float4/row
    float4 o;
    o.x = a.x + b.x + r.x + g.x;
    o.y = a.y + b.y + r.y + g.y;
    o.z = a.z + b.z + r.z + g.z;
    o.w = a.w + b.w + r.w + g.w;
    ((float4*)out)[i] = o;
}

// ---------------------------------------------------------------------------
// V transpose per head: qkv[b][n][2*DIMM + h*64 + d] -> vT[bh][d][n]
// ---------------------------------------------------------------------------
__global__ __launch_bounds__(256) void vtrans_kernel(
    const bf16* __restrict__ qkv, bf16* __restrict__ vT)
{
    __shared__ bf16 t[64 * 64];
    const int n0 = blockIdx.x * 64;
    const int bh = blockIdx.y;
    const int b = bh >> 4, h = bh & 15;
    const bf16* src = qkv + (size_t)(b * SEQ + n0) * QKV3 + 2 * DIMM + h * DHEAD;

    #pragma unroll
    for (int it = 0; it < 2; ++it) {
        const int c = it * 256 + threadIdx.x;   // 512 chunks of 8 elems
        const int n = c >> 3, d8 = (c & 7) * 8;
        const bf16x8 v8 = *(const bf16x8*)(src + (size_t)n * QKV3 + d8);
        const int byte = (n * 128 + d8 * 2) ^ (((n >> 3) & 7) << 4);
        *(bf16x8*)((char*)t + byte) = v8;
    }
    __syncthreads();
    #pragma unroll
    for (int it = 0; it < 2; ++it) {
        const int c = it * 256 + threadIdx.x;
        const int d = c >> 3, nc = c & 7;
        bf16x8 o8;
        #pragma unroll
        for (int i = 0; i < 8; ++i) {
            const int n = nc * 8 + i;
            const int byte = (n * 128 + d * 2) ^ ((nc & 7) << 4);
            o8[i] = *(const bf16*)((const char*)t + byte);
        }
        *(bf16x8*)(vT + (size_t)bh * DHEAD * SEQ + (size_t)d * SEQ + n0 + nc * 8) = o8;
    }
}

// ---------------------------------------------------------------------------
// Flash attention v6: v5 + exp2 domain. log2(e) folded into the Q scale so
// P = exp2(S2 - m2) uses v_exp_f32 directly (no per-exp v_mul). Defer-max
// threshold 8 nat -> 11.5 log2. Otherwise identical to v5 (passing).
// ---------------------------------------------------------------------------
__global__ __launch_bounds__(256, 4)
void attn_kernel(const bf16* __restrict__ qkv, const bf16* __restrict__ vT,
                 bf16* __restrict__ out)
{
    __shared__ bf16 Ks[2][64 * 64];
    __shared__ bf16 Vs[2][64 * 64];
    __shared__ bf16 Ps[4][16 * 64];
    const int bid = blockIdx.x;                    // 0..1023
    const int idx = (bid & 7) * 128 + (bid >> 3);  // bijective XCD swizzle
    const int qt = idx & 31;
    const int bh = idx >> 5;                       // 4 bh per XCD chunk
    const int b = bh >> 4, h = bh & 15;
    const int tid = threadIdx.x;
    const int lane = tid & 63, wave = tid >> 6;
    const int q = lane & 15, hi = lane >> 4;

    const bf16* qbase = qkv + (size_t)(b * SEQ) * QKV3 + h * DHEAD;
    const bf16* kbase = qbase + DIMM;
    const bf16* vbase = vT + (size_t)bh * DHEAD * SEQ;

    // Q fragment (B operand: col q, k-slots hi*8+j); scale = 0.125 * log2(e)
    const int q0 = qt * 64 + wave * 16;
    bf16x8 qf[2];
    {
        const float qs = 0.125f * 1.4426950408889634f;
        const bf16* qp = qbase + (size_t)(q0 + q) * QKV3 + (hi << 3);
        qf[0] = *(const bf16x8*)qp;
        qf[1] = *(const bf16x8*)(qp + 32);
        #pragma unroll
        for (int j = 0; j < 8; ++j) {
            qf[0][j] = (bf16)((float)qf[0][j] * qs);
            qf[1][j] = (bf16)((float)qf[1][j] * qs);
        }
    }

    // staging: wave stages LDS elems [wave*1024, +1024); pre-swizzled source
    const int srow = lane >> 3;
    const int scol = ((lane & 7) ^ srow) << 3;
    const bf16* gk = kbase + (size_t)(wave * 16 + srow) * QKV3 + scol;
    const bf16* gv = vbase + (size_t)(wave * 16 + srow) * SEQ + scol;

#define STAGE(BUF, KT) do {                                        \
        bf16* lk_ = &Ks[BUF][wave * 1024];                         \
        bf16* lv_ = &Vs[BUF][wave * 1024];                         \
        GLDS16(gk + (size_t)(KT) * QKV3,       lk_);               \
        GLDS16(gk + (size_t)((KT) + 8) * QKV3, lk_ + 512);         \
        GLDS16(gv + (KT),                      lv_);               \
        GLDS16(gv + (KT) + 8 * SEQ,            lv_ + 512);         \
    } while (0)

    float m = -1e30f, l = 0.0f;
    f32x4 o[4] = {};

    STAGE(0, 0);
    int cur = 0;
    for (int kt = 0; kt < SEQ; kt += 64) {
        __syncthreads();   // drains vmcnt(0): STAGE(kt) resident; buf cur^1 free
        if (kt + 64 < SEQ) STAGE(cur ^ 1, kt + 64);   // fire-and-forget

        // S2^T = K Q2^T (log2 domain): sv[kf][r] = S2[kv=kf*16+hi*4+r][q]
        f32x4 sv[4];
        __builtin_amdgcn_s_setprio(1);
        #pragma unroll
        for (int kf = 0; kf < 4; ++kf) {
            f32x4 z = {0.f, 0.f, 0.f, 0.f};
            sv[kf] = z;
            #pragma unroll
            for (int ks = 0; ks < 2; ++ks) {
                const int row = kf * 16 + q;
                const int bo = (row * 128 + ks * 64 + (hi << 4)) ^ ((row & 7) << 4);
                const bf16x8 kfrag = *(const bf16x8*)((const char*)&Ks[cur][0] + bo);
                sv[kf] = mfma16(kfrag, qf[ks], sv[kf]);
            }
        }
        __builtin_amdgcn_s_setprio(0);

        // in-register row max (16 values) + 2 shfl across hi-groups
        float pmax;
        {
            float a = fmaxf(fmaxf(sv[0][0], sv[0][1]), fmaxf(sv[0][2], sv[0][3]));
            float b2 = fmaxf(fmaxf(sv[1][0], sv[1][1]), fmaxf(sv[1][2], sv[1][3]));
            float c = fmaxf(fmaxf(sv[2][0], sv[2][1]), fmaxf(sv[2][2], sv[2][3]));
            float d = fmaxf(fmaxf(sv[3][0], sv[3][1]), fmaxf(sv[3][2], sv[3][3]));
            pmax = fmaxf(fmaxf(a, b2), fmaxf(c, d));
        }
        pmax = fmaxf(pmax, __shfl_xor(pmax, 16, 64));
        pmax = fmaxf(pmax, __shfl_xor(pmax, 32, 64));

        // defer-max (THR = 8 nat = 11.5 log2)
        if (__any(pmax - m > 11.5f)) {
            const float nm = fmaxf(m, pmax);
            const float fr = exp2f(m - nm);
            l *= fr;
            #pragma unroll
            for (int df = 0; df < 4; ++df) {
                o[df][0] *= fr; o[df][1] *= fr;
                o[df][2] *= fr; o[df][3] *= fr;
            }
            m = nm;
        }

        // P = exp2(S2 - m): pack 4 bf16 -> one b64 write per kf
        float rsum = 0.0f;
        #pragma unroll
        for (int kf = 0; kf < 4; ++kf) {
            float p0 = exp2f(sv[kf][0] - m);
            float p1 = exp2f(sv[kf][1] - m);
            float p2 = exp2f(sv[kf][2] - m);
            float p3 = exp2f(sv[kf][3] - m);
            rsum += (p0 + p1) + (p2 + p3);
            bf16x4 pk = { (bf16)p0, (bf16)p1, (bf16)p2, (bf16)p3 };
            const int bo = (q * 128 + kf * 32 + hi * 8) ^ ((q & 7) << 4);
            *(bf16x4*)((char*)Ps[wave] + bo) = pk;
        }
        rsum += __shfl_xor(rsum, 16, 64);
        rsum += __shfl_xor(rsum, 32, 64);
        l += rsum;

        // P B-fragments: col q, kv-slots ks*32 + hi*8 + j
        bf16x8 pf[2];
        #pragma unroll
        for (int ks = 0; ks < 2; ++ks) {
            const int bo = (q * 128 + ks * 64 + (hi << 4)) ^ ((q & 7) << 4);
            pf[ks] = *(const bf16x8*)((const char*)Ps[wave] + bo);
        }
        // O^T += V^T P^T : o[df] has col q, rows d = df*16 + hi*4 + r
        __builtin_amdgcn_s_setprio(1);
        #pragma unroll
        for (int df = 0; df < 4; ++df)
            #pragma unroll
            for (int ks = 0; ks < 2; ++ks) {
                const int rowv = df * 16 + q;
                const int bo = (rowv * 128 + ks * 64 + (hi << 4)) ^ ((rowv & 7) << 4);
                const bf16x8 vfrag = *(const bf16x8*)((const char*)&Vs[cur][0] + bo);
                o[df] = mfma16(vfrag, pf[ks], o[df]);
            }
        __builtin_amdgcn_s_setprio(0);
        cur ^= 1;
    }
#undef STAGE

    // epilogue: normalize, pack 4 bf16 (consecutive d) per 8B store
    {
        const float inv = 1.0f / l;
        const int grow = b * SEQ + q0 + q;
        #pragma unroll
        for (int df = 0; df < 4; ++df) {
            bf16x4 pk = { (bf16)(o[df][0] * inv), (bf16)(o[df][1] * inv),
                          (bf16)(o[df][2] * inv), (bf16)(o[df][3] * inv) };
            *(bf16x4*)(out + (size_t)grow * DIMM + h * DHEAD + df * 16 + hi * 4) = pk;
        }
    }
}

// ---------------------------------------------------------------------------
extern "C" void kernel_launch(void* const* d_in, const int* in_sizes, int n_in,
                              void* d_out, int out_size, void* d_ws, size_t ws_size,
                              hipStream_t stream)
{
    (void)in_sizes; (void)n_in; (void)out_size;
    const float* x    = (const float*)d_in[0];
    const float* ln1g = (const float*)d_in[1];
    const float* ln1b = (const float*)d_in[2];
    const float* ln2g = (const float*)d_in[3];
    const float* ln2b = (const float*)d_in[4];
    const float* wqkv = (const float*)d_in[5];
    const float* wout = (const float*)d_in[6];
    const float* bout = (const float*)d_in[7];
    const float* wff1 = (const float*)d_in[8];
    const float* bff1 = (const float*)d_in[9];
    const float* wff2 = (const float*)d_in[10];
    const float* bff2 = (const float*)d_in[11];

    char* ws = (char*)d_ws;
    const dim3 blk(256);
    const bool splitk = ws_size >= 92274688ULL;   // 88 MB packed layout

    if (splitk) {
        // Phase-lifetime-packed layout (all live ranges disjoint; 88 MB):
        bf16*  wff2T = (bf16*)(ws);
        bf16*  woutT = (bf16*)(ws + 8388608);
        bf16*  wff1T = (bf16*)(ws + 10485760);
        bf16*  wqkvT = (bf16*)(ws + 18874368);
        bf16*  hbuf  = (bf16*)(ws + 25165824);
        bf16*  qkvb  = (bf16*)(ws + 33554432);
        bf16*  vT    = (bf16*)(ws + 58720256);
        bf16*  attnb = (bf16*)(ws + 67108864);
        float* x2    = (float*)(ws + 75497472);
        bf16*  fbuf  = (bf16*)(ws + 41943040);
        float* p0    = (float*)(ws + 8388608);
        float* p1    = (float*)(ws + 25165824);

        tcast_kernel<<<dim3(QKV3 / 32, DIMM / 32), blk, 0, stream>>>(wqkv, wqkvT, DIMM, QKV3);
        tcast_kernel<<<dim3(DIMM / 32, DIMM / 32), blk, 0, stream>>>(wout, woutT, DIMM, DIMM);
        tcast_kernel<<<dim3(FFD  / 32, DIMM / 32), blk, 0, stream>>>(wff1, wff1T, DIMM, FFD);
        tcast_kernel<<<dim3(DIMM / 32, FFD  / 32), blk, 0, stream>>>(wff2, wff2T, FFD, DIMM);

        ln_cast_kernel<<<NROWS, blk, 0, stream>>>(x, ln1g, ln1b, hbuf);
        gemm_bt_kernel<0><<<(NROWS / 128) * (QKV3 / 128), blk, 0, stream>>>(
            hbuf, wqkvT, nullptr, nullptr, qkvb, NROWS, QKV3, DIMM, DIMM);
        vtrans_kernel<<<dim3(SEQ / 64, BATCH * NHEAD), blk, 0, stream>>>(qkvb, vT);
        attn_kernel<<<dim3(1024), blk, 0, stream>>>(qkvb, vT, attnb);
        gemm_bt_kernel<1><<<(NROWS / 128) * (DIMM / 128), blk, 0, stream>>>(
            attnb, woutT, bout, x, x2, NROWS, DIMM, DIMM, DIMM);
        ln_cast_kernel<<<NROWS, blk, 0, stream>>>(x2, ln2g, ln2b, hbuf);
        gemm_bt_kernel<2><<<(NROWS / 128) * (FFD / 128), blk, 0, stream>>>(
            hbuf, wff1T, bff1, nullptr, fbuf, NROWS, FFD, DIMM, DIMM);
        gemm_bt_kernel<3><<<2 * (NROWS / 128) * (DIMM / 128), blk, 0, stream>>>(
            fbuf, wff2T, nullptr, (const float*)p1, p0, NROWS, DIMM, FFD / 2, FFD);
        ff2_reduce_kernel<<<(NROWS * DIMM) / 1024, blk, 0, stream>>>(
            p0, p1, bff2, x2, (float*)d_out);
    } else {
        // Fallback: round-4 proven layout, single-pass FF2.
        bf16*  wqkvT = (bf16*)(ws);
        bf16*  woutT = (bf16*)(ws + 6291456);
        bf16*  wff1T = (bf16*)(ws + 8388608);
        bf16*  wff2T = (bf16*)(ws + 16777216);
        float* x2    = (float*)(ws + 25165824);
        bf16*  vT    = (bf16*)(ws + 25165824);
        bf16*  hbuf  = (bf16*)(ws + 41943040);
        bf16*  qkvb  = (bf16*)(ws + 50331648);
        bf16*  attnb = (bf16*)(ws + 75497472);
        bf16*  fbuf  = (bf16*)(ws + 50331648);

        tcast_kernel<<<dim3(QKV3 / 32, DIMM / 32), blk, 0, stream>>>(wqkv, wqkvT, DIMM, QKV3);
        tcast_kernel<<<dim3(DIMM / 32, DIMM / 32), blk, 0, stream>>>(wout, woutT, DIMM, DIMM);
        tcast_kernel<<<dim3(FFD  / 32, DIMM / 32), blk, 0, stream>>>(wff1, wff1T, DIMM, FFD);
        tcast_kernel<<<dim3(DIMM / 32, FFD  / 32), blk, 0, stream>>>(wff2, wff2T, FFD, DIMM);

        ln_cast_kernel<<<NROWS, blk, 0, stream>>>(x, ln1g, ln1b, hbuf);
        gemm_bt_kernel<0><<<(NROWS / 128) * (QKV3 / 128), blk, 0, stream>>>(
            hbuf, wqkvT, nullptr, nullptr, qkvb, NROWS, QKV3, DIMM, DIMM);
        vtrans_kernel<<<dim3(SEQ / 64, BATCH * NHEAD), blk, 0, stream>>>(qkvb, vT);
        attn_kernel<<<dim3(1024), blk, 0, stream>>>(qkvb, vT, attnb);
        gemm_bt_kernel<1><<<(NROWS / 128) * (DIMM / 128), blk, 0, stream>>>(
            attnb, woutT, bout, x, x2, NROWS, DIMM, DIMM, DIMM);
        ln_cast_kernel<<<NROWS, blk, 0, stream>>>(x2, ln2g, ln2b, hbuf);
        gemm_bt_kernel<2><<<(NROWS / 128) * (FFD / 128), blk, 0, stream>>>(
            hbuf, wff1T, bff1, nullptr, fbuf, NROWS, FFD, DIMM, DIMM);
        gemm_bt_kernel<1><<<(NROWS / 128) * (DIMM / 128), blk, 0, stream>>>(
            fbuf, wff2T, bff2, x2, (float*)d_out, NROWS, DIMM, FFD, FFD);
    }
}

// Round 9
// 277.604 us; speedup vs baseline: 1.0330x; 1.0330x over previous
//
#include <hip/hip_runtime.h>
#include <hip/hip_bf16.h>
#include <math.h>

#define SEQ   2048
#define BATCH 2
#define NROWS 4096      /* BATCH*SEQ */
#define DIMM  1024
#define QKV3  3072
#define FFD   4096
#define NHEAD 16
#define DHEAD 64

typedef __bf16 bf16;
typedef __bf16 bf16x4 __attribute__((ext_vector_type(4)));
typedef __bf16 bf16x8 __attribute__((ext_vector_type(8)));
typedef float  f32x4  __attribute__((ext_vector_type(4)));

static __device__ __forceinline__ f32x4 mfma16(bf16x8 a, bf16x8 b, f32x4 c) {
    return __builtin_amdgcn_mfma_f32_16x16x32_bf16(a, b, c, 0, 0, 0);
}

#define GLDS16(gp, lp) __builtin_amdgcn_global_load_lds( \
    (__attribute__((address_space(1))) void*)(gp),       \
    (__attribute__((address_space(3))) void*)(lp), 16, 0, 0)

// ---------------------------------------------------------------------------
// Transpose + cast: src fp32 [K][N] -> dst bf16 [N][K]
// ---------------------------------------------------------------------------
__global__ __launch_bounds__(256) void tcast_kernel(
    const float* __restrict__ src, bf16* __restrict__ dst, int K, int N)
{
    __shared__ float tile[32][33];
    const int n0 = blockIdx.x * 32;
    const int k0 = blockIdx.y * 32;
    const int r = threadIdx.x >> 5;   // 0..7
    const int c = threadIdx.x & 31;
    #pragma unroll
    for (int i = 0; i < 4; ++i)
        tile[r + 8 * i][c] = src[(size_t)(k0 + r + 8 * i) * N + n0 + c];
    __syncthreads();
    #pragma unroll
    for (int i = 0; i < 4; ++i)
        dst[(size_t)(n0 + r + 8 * i) * K + k0 + c] = (bf16)tile[c][r + 8 * i];
}

// ---------------------------------------------------------------------------
// LayerNorm fp32 [NROWS][1024] -> bf16, one block per row
// ---------------------------------------------------------------------------
__global__ __launch_bounds__(256) void ln_cast_kernel(
    const float* __restrict__ x, const float* __restrict__ g,
    const float* __restrict__ b, bf16* __restrict__ out)
{
    const int row = blockIdx.x;
    const int t = threadIdx.x;
    const float4 v = ((const float4*)(x + (size_t)row * DIMM))[t];
    float s  = v.x + v.y + v.z + v.w;
    float sq = v.x * v.x + v.y * v.y + v.z * v.z + v.w * v.w;
    #pragma unroll
    for (int m = 1; m < 64; m <<= 1) {
        s  += __shfl_xor(s, m, 64);
        sq += __shfl_xor(sq, m, 64);
    }
    __shared__ float ss[4], ssq[4];
    const int wave = t >> 6;
    if ((t & 63) == 0) { ss[wave] = s; ssq[wave] = sq; }
    __syncthreads();
    s  = ss[0] + ss[1] + ss[2] + ss[3];
    sq = ssq[0] + ssq[1] + ssq[2] + ssq[3];
    const float mean = s * (1.0f / DIMM);
    const float var  = sq * (1.0f / DIMM) - mean * mean;
    const float rs   = rsqrtf(var + 1e-5f);
    const float4 gv = ((const float4*)g)[t];
    const float4 bv = ((const float4*)b)[t];
    bf16* o = out + (size_t)row * DIMM + t * 4;
    o[0] = (bf16)((v.x - mean) * rs * gv.x + bv.x);
    o[1] = (bf16)((v.y - mean) * rs * gv.y + bv.y);
    o[2] = (bf16)((v.z - mean) * rs * gv.z + bv.z);
    o[3] = (bf16)((v.w - mean) * rs * gv.w + bv.w);
}

// ---------------------------------------------------------------------------
// bf16 MFMA GEMM, 3-stage counted-vmcnt pipeline (T4 mechanism):
//   prologue stages tiles 0,1,2 (12 glds in flight). Per K-step:
//   s_waitcnt vmcnt(8)  -> own tile-k loads done, k+1/k+2 STAY IN FLIGHT
//   s_barrier           -> all waves' tile-k data resident (per-wave staging)
//   compute(k)          -> ds_read + 16 MFMA
//   s_barrier           -> everyone done reading buf k -> safe to overwrite
//   STAGE(k+3) into buf k (fire-and-forget; lands ~3 compute phases later)
// Never drains vmcnt to 0 in steady state (tail: vmcnt 8/4/0 cases).
// C[M][N] = A[M][K] @ B[K][N], BT[N][K] input, row stride ld. 128x128 tile,
// BK=32, 4 waves, 4x4 16x16x32 frags. XCD-chunk swizzle (T1).
// EPI: 0 = bf16 out; 1 = +bias +residual, fp32 out; 2 = +bias, GELU, bf16 out
//      3 = split-K partial (ks = idx / tiles; partial to ks==0?Cout:res)
// ---------------------------------------------------------------------------
template<int EPI>
__global__ __launch_bounds__(256, 3)
void gemm_bt_kernel(const bf16* __restrict__ A, const bf16* __restrict__ BT,
                    const float* __restrict__ bias, const float* __restrict__ res,
                    void* __restrict__ Cout, int M, int N, int K, int ld)
{
    __shared__ bf16 As[3][4096];   // [buf][128 m][32 k]
    __shared__ bf16 Bs[3][4096];
    const int nb = N >> 7;
    const int chunk = (int)gridDim.x >> 3;
    int idx = (blockIdx.x & 7) * chunk + (blockIdx.x >> 3);
    int ks = 0;
    if (EPI == 3) {
        const int tiles = (M >> 7) * nb;
        ks = idx / tiles;
        idx -= ks * tiles;
    }
    const int bm = idx / nb, bn = idx - bm * nb;
    const int tm = bm << 7, tn = bn << 7;
    const int tid = threadIdx.x;
    const int lane = tid & 63, wave = tid >> 6;
    const int wm = (wave >> 1) << 6, wn = (wave & 1) << 6;
    const int kofs = ks * K;   // column offset for split-K slice

    const bf16* ga = A  + (size_t)(tm + wave * 32 + (lane >> 2)) * ld + kofs + ((lane & 3) << 3);
    const bf16* gb = BT + (size_t)(tn + wave * 32 + (lane >> 2)) * ld + kofs + ((lane & 3) << 3);
    const size_t k16 = (size_t)16 * ld;

    f32x4 acc[4][4] = {};
    const int ro = (lane & 15) * 32 + ((lane >> 4) << 3);

#define GSTAGE(BUF, KO) do {                          \
        bf16* la_ = &As[BUF][wave * 1024];            \
        bf16* lb_ = &Bs[BUF][wave * 1024];            \
        GLDS16(ga + (KO),       la_);                 \
        GLDS16(ga + (KO) + k16, la_ + 512);           \
        GLDS16(gb + (KO),       lb_);                 \
        GLDS16(gb + (KO) + k16, lb_ + 512);           \
    } while (0)

    GSTAGE(0, 0);
    GSTAGE(1, 32);
    GSTAGE(2, 64);
    int cur = 0;
    for (int k0 = 0; k0 < K; k0 += 32) {
        // wait own tile-k loads only; leave future tiles' loads in flight
        if (k0 + 96 <= K)      asm volatile("s_waitcnt vmcnt(8)" ::: "memory");
        else if (k0 + 64 <= K) asm volatile("s_waitcnt vmcnt(4)" ::: "memory");
        else                   asm volatile("s_waitcnt vmcnt(0)" ::: "memory");
        __builtin_amdgcn_s_barrier();

        bf16x8 af[4], bfr[4];
        #pragma unroll
        for (int i = 0; i < 4; ++i) {
            af[i]  = *(const bf16x8*)(&As[cur][0] + (wm + i * 16) * 32 + ro);
            bfr[i] = *(const bf16x8*)(&Bs[cur][0] + (wn + i * 16) * 32 + ro);
        }
        #pragma unroll
        for (int i = 0; i < 4; ++i)
            #pragma unroll
            for (int j = 0; j < 4; ++j)
                acc[i][j] = mfma16(af[i], bfr[j], acc[i][j]);

        asm volatile("" ::: "memory");
        __builtin_amdgcn_s_barrier();   // all waves done reading buf cur
        asm volatile("" ::: "memory");
        if (k0 + 96 < K) GSTAGE(cur, k0 + 96);   // refill freed buffer
        cur = (cur == 2) ? 0 : cur + 1;
    }
#undef GSTAGE

    const int r0 = tm + wm + ((lane >> 4) << 2);
    const int c0 = tn + wn + (lane & 15);
    if (EPI == 0) {
        bf16* C = (bf16*)Cout;
        #pragma unroll
        for (int i = 0; i < 4; ++i)
            #pragma unroll
            for (int j = 0; j < 4; ++j)
                #pragma unroll
                for (int r = 0; r < 4; ++r)
                    C[(size_t)(r0 + i * 16 + r) * N + (c0 + j * 16)] = (bf16)acc[i][j][r];
    } else if (EPI == 1) {
        float* C = (float*)Cout;
        #pragma unroll
        for (int j = 0; j < 4; ++j) {
            const float bv = bias[c0 + j * 16];
            #pragma unroll
            for (int i = 0; i < 4; ++i)
                #pragma unroll
                for (int r = 0; r < 4; ++r) {
                    const size_t idx2 = (size_t)(r0 + i * 16 + r) * N + (c0 + j * 16);
                    C[idx2] = acc[i][j][r] + bv + res[idx2];
                }
        }
    } else if (EPI == 2) {
        bf16* C = (bf16*)Cout;
        #pragma unroll
        for (int j = 0; j < 4; ++j) {
            const float bv = bias[c0 + j * 16];
            #pragma unroll
            for (int i = 0; i < 4; ++i)
                #pragma unroll
                for (int r = 0; r < 4; ++r) {
                    const float v = acc[i][j][r] + bv;
                    const float gl = 0.5f * v * (1.0f + erff(v * 0.70710678118654752f));
                    C[(size_t)(r0 + i * 16 + r) * N + (c0 + j * 16)] = (bf16)gl;
                }
        }
    } else {   // EPI == 3: fp32 partial, slice ks
        float* C = (float*)(ks == 0 ? Cout : (void*)res);
        #pragma unroll
        for (int j = 0; j < 4; ++j)
            #pragma unroll
            for (int i = 0; i < 4; ++i)
                #pragma unroll
                for (int r = 0; r < 4; ++r)
                    C[(size_t)(r0 + i * 16 + r) * N + (c0 + j * 16)] = acc[i][j][r];
    }
}

// ---------------------------------------------------------------------------
// FF2 split-K reduce: out = p0 + p1 + bias + res  (all fp32, [NROWS][DIMM])
// ---------------------------------------------------------------------------
__global__ __launch_bounds__(256) void ff2_reduce_kernel(
    const float* __restrict__ p0, const float* __restrict__ p1,
    const float* __restrict__ bias, const float* __restrict__ res,
    float* __restrict__ out)
{
    const int i = blockIdx.x * 256 + threadIdx.x;    // float4 index
    const float4 a = ((const float4*)p0)[i];
    const float4 b = ((const float4*)p1)[i];
    const float4 r = ((const float4*)res)[i];
    const float4 g = ((const float4*)bias)[i & 255]; // DIMM/4 = 256 float4/row
    float4 o;
    o.x = a.x + b.x + r.x + g.x;
    o.y = a.y + b.y + r.y + g.y;
    o.z = a.z + b.z + r.z + g.z;
    o.w = a.w + b.w + r.w + g.w;
    ((float4*)out)[i] = o;
}

// ---------------------------------------------------------------------------
// V transpose per head: qkv[b][n][2*DIMM + h*64 + d] -> vT[bh][d][n]
// ---------------------------------------------------------------------------
__global__ __launch_bounds__(256) void vtrans_kernel(
    const bf16* __restrict__ qkv, bf16* __restrict__ vT)
{
    __shared__ bf16 t[64 * 64];
    const int n0 = blockIdx.x * 64;
    const int bh = blockIdx.y;
    const int b = bh >> 4, h = bh & 15;
    const bf16* src = qkv + (size_t)(b * SEQ + n0) * QKV3 + 2 * DIMM + h * DHEAD;

    #pragma unroll
    for (int it = 0; it < 2; ++it) {
        const int c = it * 256 + threadIdx.x;   // 512 chunks of 8 elems
        const int n = c >> 3, d8 = (c & 7) * 8;
        const bf16x8 v8 = *(const bf16x8*)(src + (size_t)n * QKV3 + d8);
        const int byte = (n * 128 + d8 * 2) ^ (((n >> 3) & 7) << 4);
        *(bf16x8*)((char*)t + byte) = v8;
    }
    __syncthreads();
    #pragma unroll
    for (int it = 0; it < 2; ++it) {
        const int c = it * 256 + threadIdx.x;
        const int d = c >> 3, nc = c & 7;
        bf16x8 o8;
        #pragma unroll
        for (int i = 0; i < 8; ++i) {
            const int n = nc * 8 + i;
            const int byte = (n * 128 + d * 2) ^ ((nc & 7) << 4);
            o8[i] = *(const bf16*)((const char*)t + byte);
        }
        *(bf16x8*)(vT + (size_t)bh * DHEAD * SEQ + (size_t)d * SEQ + n0 + nc * 8) = o8;
    }
}

// ---------------------------------------------------------------------------
// Flash attention v5 (r7-proven, 74 us): exp2 experiment REVERTED (__expf is
// native v_mul+v_exp; plain exp2f lowers to the slow precise OCML path).
// ---------------------------------------------------------------------------
__global__ __launch_bounds__(256, 4)
void attn_kernel(const bf16* __restrict__ qkv, const bf16* __restrict__ vT,
                 bf16* __restrict__ out)
{
    __shared__ bf16 Ks[2][64 * 64];
    __shared__ bf16 Vs[2][64 * 64];
    __shared__ bf16 Ps[4][16 * 64];
    const int bid = blockIdx.x;                    // 0..1023
    const int idx = (bid & 7) * 128 + (bid >> 3);  // bijective XCD swizzle
    const int qt = idx & 31;
    const int bh = idx >> 5;                       // 4 bh per XCD chunk
    const int b = bh >> 4, h = bh & 15;
    const int tid = threadIdx.x;
    const int lane = tid & 63, wave = tid >> 6;
    const int q = lane & 15, hi = lane >> 4;

    const bf16* qbase = qkv + (size_t)(b * SEQ) * QKV3 + h * DHEAD;
    const bf16* kbase = qbase + DIMM;
    const bf16* vbase = vT + (size_t)bh * DHEAD * SEQ;

    // Q fragment (B operand: col q, k-slots hi*8+j), scale 1/8 folded in
    const int q0 = qt * 64 + wave * 16;
    bf16x8 qf[2];
    {
        const bf16* qp = qbase + (size_t)(q0 + q) * QKV3 + (hi << 3);
        qf[0] = *(const bf16x8*)qp;
        qf[1] = *(const bf16x8*)(qp + 32);
        #pragma unroll
        for (int j = 0; j < 8; ++j) {
            qf[0][j] = (bf16)((float)qf[0][j] * 0.125f);
            qf[1][j] = (bf16)((float)qf[1][j] * 0.125f);
        }
    }

    // staging: wave stages LDS elems [wave*1024, +1024); pre-swizzled source
    const int srow = lane >> 3;
    const int scol = ((lane & 7) ^ srow) << 3;
    const bf16* gk = kbase + (size_t)(wave * 16 + srow) * QKV3 + scol;
    const bf16* gv = vbase + (size_t)(wave * 16 + srow) * SEQ + scol;

#define STAGE(BUF, KT) do {                                        \
        bf16* lk_ = &Ks[BUF][wave * 1024];                         \
        bf16* lv_ = &Vs[BUF][wave * 1024];                         \
        GLDS16(gk + (size_t)(KT) * QKV3,       lk_);               \
        GLDS16(gk + (size_t)((KT) + 8) * QKV3, lk_ + 512);         \
        GLDS16(gv + (KT),                      lv_);               \
        GLDS16(gv + (KT) + 8 * SEQ,            lv_ + 512);         \
    } while (0)

    float m = -1e30f, l = 0.0f;
    f32x4 o[4] = {};

    STAGE(0, 0);
    int cur = 0;
    for (int kt = 0; kt < SEQ; kt += 64) {
        __syncthreads();   // drains vmcnt(0): STAGE(kt) resident; buf cur^1 free
        if (kt + 64 < SEQ) STAGE(cur ^ 1, kt + 64);   // fire-and-forget

        // S^T = K Q^T : sv[kf][r] = S[kv=kf*16+hi*4+r][q]
        f32x4 sv[4];
        __builtin_amdgcn_s_setprio(1);
        #pragma unroll
        for (int kf = 0; kf < 4; ++kf) {
            f32x4 z = {0.f, 0.f, 0.f, 0.f};
            sv[kf] = z;
            #pragma unroll
            for (int ks = 0; ks < 2; ++ks) {
                const int row = kf * 16 + q;
                const int bo = (row * 128 + ks * 64 + (hi << 4)) ^ ((row & 7) << 4);
                const bf16x8 kfrag = *(const bf16x8*)((const char*)&Ks[cur][0] + bo);
                sv[kf] = mfma16(kfrag, qf[ks], sv[kf]);
            }
        }
        __builtin_amdgcn_s_setprio(0);

        // in-register row max (16 values) + 2 shfl across hi-groups
        float pmax;
        {
            float a = fmaxf(fmaxf(sv[0][0], sv[0][1]), fmaxf(sv[0][2], sv[0][3]));
            float b2 = fmaxf(fmaxf(sv[1][0], sv[1][1]), fmaxf(sv[1][2], sv[1][3]));
            float c = fmaxf(fmaxf(sv[2][0], sv[2][1]), fmaxf(sv[2][2], sv[2][3]));
            float d = fmaxf(fmaxf(sv[3][0], sv[3][1]), fmaxf(sv[3][2], sv[3][3]));
            pmax = fmaxf(fmaxf(a, b2), fmaxf(c, d));
        }
        pmax = fmaxf(pmax, __shfl_xor(pmax, 16, 64));
        pmax = fmaxf(pmax, __shfl_xor(pmax, 32, 64));

        // defer-max (THR=8)
        if (__any(pmax - m > 8.0f)) {
            const float nm = fmaxf(m, pmax);
            const float fr = __expf(m - nm);
            l *= fr;
            #pragma unroll
            for (int df = 0; df < 4; ++df) {
                o[df][0] *= fr; o[df][1] *= fr;
                o[df][2] *= fr; o[df][3] *= fr;
            }
            m = nm;
        }

        // P = exp(S - m): pack 4 bf16 -> one b64 write per kf
        float rsum = 0.0f;
        #pragma unroll
        for (int kf = 0; kf < 4; ++kf) {
            float p0 = __expf(sv[kf][0] - m);
            float p1 = __expf(sv[kf][1] - m);
            float p2 = __expf(sv[kf][2] - m);
            float p3 = __expf(sv[kf][3] - m);
            rsum += (p0 + p1) + (p2 + p3);
            bf16x4 pk = { (bf16)p0, (bf16)p1, (bf16)p2, (bf16)p3 };
            const int bo = (q * 128 + kf * 32 + hi * 8) ^ ((q & 7) << 4);
            *(bf16x4*)((char*)Ps[wave] + bo) = pk;
        }
        rsum += __shfl_xor(rsum, 16, 64);
        rsum += __shfl_xor(rsum, 32, 64);
        l += rsum;

        // P B-fragments: col q, kv-slots ks*32 + hi*8 + j
        bf16x8 pf[2];
        #pragma unroll
        for (int ks = 0; ks < 2; ++ks) {
            const int bo = (q * 128 + ks * 64 + (hi << 4)) ^ ((q & 7) << 4);
            pf[ks] = *(const bf16x8*)((const char*)Ps[wave] + bo);
        }
        // O^T += V^T P^T : o[df] has col q, rows d = df*16 + hi*4 + r
        __builtin_amdgcn_s_setprio(1);
        #pragma unroll
        for (int df = 0; df < 4; ++df)
            #pragma unroll
            for (int ks = 0; ks < 2; ++ks) {
                const int rowv = df * 16 + q;
                const int bo = (rowv * 128 + ks * 64 + (hi << 4)) ^ ((rowv & 7) << 4);
                const bf16x8 vfrag = *(const bf16x8*)((const char*)&Vs[cur][0] + bo);
                o[df] = mfma16(vfrag, pf[ks], o[df]);
            }
        __builtin_amdgcn_s_setprio(0);
        cur ^= 1;
    }
#undef STAGE

    // epilogue: normalize, pack 4 bf16 (consecutive d) per 8B store
    {
        const float inv = 1.0f / l;
        const int grow = b * SEQ + q0 + q;
        #pragma unroll
        for (int df = 0; df < 4; ++df) {
            bf16x4 pk = { (bf16)(o[df][0] * inv), (bf16)(o[df][1] * inv),
                          (bf16)(o[df][2] * inv), (bf16)(o[df][3] * inv) };
            *(bf16x4*)(out + (size_t)grow * DIMM + h * DHEAD + df * 16 + hi * 4) = pk;
        }
    }
}

// ---------------------------------------------------------------------------
extern "C" void kernel_launch(void* const* d_in, const int* in_sizes, int n_in,
                              void* d_out, int out_size, void* d_ws, size_t ws_size,
                              hipStream_t stream)
{
    (void)in_sizes; (void)n_in; (void)out_size;
    const float* x    = (const float*)d_in[0];
    const float* ln1g = (const float*)d_in[1];
    const float* ln1b = (const float*)d_in[2];
    const float* ln2g = (const float*)d_in[3];
    const float* ln2b = (const float*)d_in[4];
    const float* wqkv = (const float*)d_in[5];
    const float* wout = (const float*)d_in[6];
    const float* bout = (const float*)d_in[7];
    const float* wff1 = (const float*)d_in[8];
    const float* bff1 = (const float*)d_in[9];
    const float* wff2 = (const float*)d_in[10];
    const float* bff2 = (const float*)d_in[11];

    char* ws = (char*)d_ws;
    const dim3 blk(256);
    const bool splitk = ws_size >= 92274688ULL;   // 88 MB packed layout

    if (splitk) {
        // Phase-lifetime-packed layout (all live ranges disjoint; 88 MB):
        bf16*  wff2T = (bf16*)(ws);
        bf16*  woutT = (bf16*)(ws + 8388608);
        bf16*  wff1T = (bf16*)(ws + 10485760);
        bf16*  wqkvT = (bf16*)(ws + 18874368);
        bf16*  hbuf  = (bf16*)(ws + 25165824);
        bf16*  qkvb  = (bf16*)(ws + 33554432);
        bf16*  vT    = (bf16*)(ws + 58720256);
        bf16*  attnb = (bf16*)(ws + 67108864);
        float* x2    = (float*)(ws + 75497472);
        bf16*  fbuf  = (bf16*)(ws + 41943040);
        float* p0    = (float*)(ws + 8388608);
        float* p1    = (float*)(ws + 25165824);

        tcast_kernel<<<dim3(QKV3 / 32, DIMM / 32), blk, 0, stream>>>(wqkv, wqkvT, DIMM, QKV3);
        tcast_kernel<<<dim3(DIMM / 32, DIMM / 32), blk, 0, stream>>>(wout, woutT, DIMM, DIMM);
        tcast_kernel<<<dim3(FFD  / 32, DIMM / 32), blk, 0, stream>>>(wff1, wff1T, DIMM, FFD);
        tcast_kernel<<<dim3(DIMM / 32, FFD  / 32), blk, 0, stream>>>(wff2, wff2T, FFD, DIMM);

        ln_cast_kernel<<<NROWS, blk, 0, stream>>>(x, ln1g, ln1b, hbuf);
        gemm_bt_kernel<0><<<(NROWS / 128) * (QKV3 / 128), blk, 0, stream>>>(
            hbuf, wqkvT, nullptr, nullptr, qkvb, NROWS, QKV3, DIMM, DIMM);
        vtrans_kernel<<<dim3(SEQ / 64, BATCH * NHEAD), blk, 0, stream>>>(qkvb, vT);
        attn_kernel<<<dim3(1024), blk, 0, stream>>>(qkvb, vT, attnb);
        gemm_bt_kernel<1><<<(NROWS / 128) * (DIMM / 128), blk, 0, stream>>>(
            attnb, woutT, bout, x, x2, NROWS, DIMM, DIMM, DIMM);
        ln_cast_kernel<<<NROWS, blk, 0, stream>>>(x2, ln2g, ln2b, hbuf);
        gemm_bt_kernel<2><<<(NROWS / 128) * (FFD / 128), blk, 0, stream>>>(
            hbuf, wff1T, bff1, nullptr, fbuf, NROWS, FFD, DIMM, DIMM);
        gemm_bt_kernel<3><<<2 * (NROWS / 128) * (DIMM / 128), blk, 0, stream>>>(
            fbuf, wff2T, nullptr, (const float*)p1, p0, NROWS, DIMM, FFD / 2, FFD);
        ff2_reduce_kernel<<<(NROWS * DIMM) / 1024, blk, 0, stream>>>(
            p0, p1, bff2, x2, (float*)d_out);
    } else {
        // Fallback: single-pass FF2, r4 layout.
        bf16*  wqkvT = (bf16*)(ws);
        bf16*  woutT = (bf16*)(ws + 6291456);
        bf16*  wff1T = (bf16*)(ws + 8388608);
        bf16*  wff2T = (bf16*)(ws + 16777216);
        float* x2    = (float*)(ws + 25165824);
        bf16*  vT    = (bf16*)(ws + 25165824);
        bf16*  hbuf  = (bf16*)(ws + 41943040);
        bf16*  qkvb  = (bf16*)(ws + 50331648);
        bf16*  attnb = (bf16*)(ws + 75497472);
        bf16*  fbuf  = (bf16*)(ws + 50331648);

        tcast_kernel<<<dim3(QKV3 / 32, DIMM / 32), blk, 0, stream>>>(wqkv, wqkvT, DIMM, QKV3);
        tcast_kernel<<<dim3(DIMM / 32, DIMM / 32), blk, 0, stream>>>(wout, woutT, DIMM, DIMM);
        tcast_kernel<<<dim3(FFD  / 32, DIMM / 32), blk, 0, stream>>>(wff1, wff1T, DIMM, FFD);
        tcast_kernel<<<dim3(DIMM / 32, FFD  / 32), blk, 0, stream>>>(wff2, wff2T, FFD, DIMM);

        ln_cast_kernel<<<NROWS, blk, 0, stream>>>(x, ln1g, ln1b, hbuf);
        gemm_bt_kernel<0><<<(NROWS / 128) * (QKV3 / 128), blk, 0, stream>>>(
            hbuf, wqkvT, nullptr, nullptr, qkvb, NROWS, QKV3, DIMM, DIMM);
        vtrans_kernel<<<dim3(SEQ / 64, BATCH * NHEAD), blk, 0, stream>>>(qkvb, vT);
        attn_kernel<<<dim3(1024), blk, 0, stream>>>(qkvb, vT, attnb);
        gemm_bt_kernel<1><<<(NROWS / 128) * (DIMM / 128), blk, 0, stream>>>(
            attnb, woutT, bout, x, x2, NROWS, DIMM, DIMM, DIMM);
        ln_cast_kernel<<<NROWS, blk, 0, stream>>>(x2, ln2g, ln2b, hbuf);
        gemm_bt_kernel<2><<<(NROWS / 128) * (FFD / 128), blk, 0, stream>>>(
            hbuf, wff1T, bff1, nullptr, fbuf, NROWS, FFD, DIMM, DIMM);
        gemm_bt_kernel<1><<<(NROWS / 128) * (DIMM / 128), blk, 0, stream>>>(
            fbuf, wff2T, bff2, x2, (float*)d_out, NROWS, DIMM, FFD, FFD);
    }
}

// Round 10
// 270.911 us; speedup vs baseline: 1.0585x; 1.0247x over previous
//
#include <hip/hip_runtime.h>
#include <hip/hip_bf16.h>
#include <math.h>

#define SEQ   2048
#define BATCH 2
#define NROWS 4096      /* BATCH*SEQ */
#define DIMM  1024
#define QKV3  3072
#define FFD   4096
#define NHEAD 16
#define DHEAD 64

typedef __bf16 bf16;
typedef __bf16 bf16x4 __attribute__((ext_vector_type(4)));
typedef __bf16 bf16x8 __attribute__((ext_vector_type(8)));
typedef float  f32x4  __attribute__((ext_vector_type(4)));

static __device__ __forceinline__ f32x4 mfma16(bf16x8 a, bf16x8 b, f32x4 c) {
    return __builtin_amdgcn_mfma_f32_16x16x32_bf16(a, b, c, 0, 0, 0);
}

#define GLDS16(gp, lp) __builtin_amdgcn_global_load_lds( \
    (__attribute__((address_space(1))) void*)(gp),       \
    (__attribute__((address_space(3))) void*)(lp), 16, 0, 0)

// ---------------------------------------------------------------------------
// Transpose + cast: src fp32 [K][N] -> dst bf16 [N][K]
// ---------------------------------------------------------------------------
__global__ __launch_bounds__(256) void tcast_kernel(
    const float* __restrict__ src, bf16* __restrict__ dst, int K, int N)
{
    __shared__ float tile[32][33];
    const int n0 = blockIdx.x * 32;
    const int k0 = blockIdx.y * 32;
    const int r = threadIdx.x >> 5;   // 0..7
    const int c = threadIdx.x & 31;
    #pragma unroll
    for (int i = 0; i < 4; ++i)
        tile[r + 8 * i][c] = src[(size_t)(k0 + r + 8 * i) * N + n0 + c];
    __syncthreads();
    #pragma unroll
    for (int i = 0; i < 4; ++i)
        dst[(size_t)(n0 + r + 8 * i) * K + k0 + c] = (bf16)tile[c][r + 8 * i];
}

// ---------------------------------------------------------------------------
// LayerNorm fp32 [NROWS][1024] -> bf16, one block per row
// ---------------------------------------------------------------------------
__global__ __launch_bounds__(256) void ln_cast_kernel(
    const float* __restrict__ x, const float* __restrict__ g,
    const float* __restrict__ b, bf16* __restrict__ out)
{
    const int row = blockIdx.x;
    const int t = threadIdx.x;
    const float4 v = ((const float4*)(x + (size_t)row * DIMM))[t];
    float s  = v.x + v.y + v.z + v.w;
    float sq = v.x * v.x + v.y * v.y + v.z * v.z + v.w * v.w;
    #pragma unroll
    for (int m = 1; m < 64; m <<= 1) {
        s  += __shfl_xor(s, m, 64);
        sq += __shfl_xor(sq, m, 64);
    }
    __shared__ float ss[4], ssq[4];
    const int wave = t >> 6;
    if ((t & 63) == 0) { ss[wave] = s; ssq[wave] = sq; }
    __syncthreads();
    s  = ss[0] + ss[1] + ss[2] + ss[3];
    sq = ssq[0] + ssq[1] + ssq[2] + ssq[3];
    const float mean = s * (1.0f / DIMM);
    const float var  = sq * (1.0f / DIMM) - mean * mean;
    const float rs   = rsqrtf(var + 1e-5f);
    const float4 gv = ((const float4*)g)[t];
    const float4 bv = ((const float4*)b)[t];
    bf16* o = out + (size_t)row * DIMM + t * 4;
    o[0] = (bf16)((v.x - mean) * rs * gv.x + bv.x);
    o[1] = (bf16)((v.y - mean) * rs * gv.y + bv.y);
    o[2] = (bf16)((v.z - mean) * rs * gv.z + bv.z);
    o[3] = (bf16)((v.w - mean) * rs * gv.w + bv.w);
}

// ---------------------------------------------------------------------------
// 256x256 8-wave GEMM (T3-direction structure + T2 swizzle + T5 setprio).
//   8 waves = 512 thr, wave (wr,wc) = (w>>2, w&3) owns a 128x64 output tile
//   (8 M-frags x 4 N-frags of 16x16). BK=64. LDS 128KB: [2 dbuf][2 halves]
//   x 128rows x 64k bf16 for A and B. K-loop: 1 tile ahead in flight,
//   counted s_waitcnt vmcnt(8) (never drains mid-loop), raw barriers
//   (r9-proven pattern), 4 compute phases/tile x 16 MFMA (64 MFMA/barrier).
//   LDS swizzle byte ^= ((row&7)<<4), applied BOTH sides (rule #21):
//   linear glds dest + inverse-swizzled per-lane global source + swizzled
//   ds_read. Residual conflict 2-way (free, m136).
//   Requires: M%256==0, N%256==0, K%64==0, K>=128, gridDim.x%8==0.
// EPI: 0 = bf16 out; 2 = +bias, GELU, bf16 out
// ---------------------------------------------------------------------------
template<int EPI>
__global__ __launch_bounds__(512, 2)
void gemm256_kernel(const bf16* __restrict__ A, const bf16* __restrict__ BT,
                    const float* __restrict__ bias, bf16* __restrict__ C,
                    int M, int N, int K, int ld)
{
    __shared__ bf16 As_[2][2][8192];   // [dbuf][half][128 rows x 64 k]
    __shared__ bf16 Bs_[2][2][8192];
    const int nb = N >> 8;
    const int chunk = (int)gridDim.x >> 3;
    const int idx = ((int)blockIdx.x & 7) * chunk + ((int)blockIdx.x >> 3);
    const int bm = idx / nb, bn = idx - bm * nb;
    const int tm = bm << 8, tn = bn << 8;
    const int tid = threadIdx.x;
    const int lane = tid & 63, w = tid >> 6;   // 8 waves
    const int wr = w >> 2, wc = w & 3;
    const int lq = lane & 15, hk = lane >> 4;

    // --- staging addresses (per-lane, inverse-swizzled source) ---
    // LDS linear byte b = L*8192 + w*1024 + lane*16 -> row = L*64+w*8+(lane>>3),
    // granule gg = lane&7. Element stored there must be global k-granule
    // g = gg ^ (row&7) = (lane&7) ^ (lane>>3)   [w*8 == 0 mod 8].
    const int sr  = lane >> 3;                        // 0..7
    const int sgo = (((lane & 7) ^ sr) << 3);         // k element offset 0..56
    const bf16* gA0 = A  + (size_t)(tm +       w * 8 + sr) * ld + sgo;
    const bf16* gA1 = A  + (size_t)(tm + 128 + w * 8 + sr) * ld + sgo;
    const bf16* gB0 = BT + (size_t)(tn +       w * 8 + sr) * ld + sgo;
    const bf16* gB1 = BT + (size_t)(tn + 128 + w * 8 + sr) * ld + sgo;
    const size_t l64 = (size_t)64 * ld;

#define STG(D, T) do {                                                   \
        const size_t ko_ = (size_t)(T) * 64;                             \
        GLDS16(gA0 + ko_,       &As_[D][0][w * 512]);                    \
        GLDS16(gA0 + ko_ + l64, &As_[D][0][4096 + w * 512]);             \
        GLDS16(gA1 + ko_,       &As_[D][1][w * 512]);                    \
        GLDS16(gA1 + ko_ + l64, &As_[D][1][4096 + w * 512]);             \
        GLDS16(gB0 + ko_,       &Bs_[D][0][w * 512]);                    \
        GLDS16(gB0 + ko_ + l64, &Bs_[D][0][4096 + w * 512]);             \
        GLDS16(gB1 + ko_,       &Bs_[D][1][w * 512]);                    \
        GLDS16(gB1 + ko_ + l64, &Bs_[D][1][4096 + w * 512]);             \
    } while (0)

    f32x4 acc[8][4] = {};

    const int NT = K >> 6;
    STG(0, 0);
    STG(1, 1);
    for (int t = 0; t < NT; ++t) {
        const int d = t & 1;
        // wait own tile-t loads (8 oldest); keep tile t+1's 8 in flight
        if (t + 1 < NT) asm volatile("s_waitcnt vmcnt(8)" ::: "memory");
        else            asm volatile("s_waitcnt vmcnt(0)" ::: "memory");
        __builtin_amdgcn_s_barrier();

        const char* Ah = (const char*)&As_[d][wr][0];
        const char* Bh = (const char*)&Bs_[d][wc >> 1][0];
        #pragma unroll
        for (int q = 0; q < 4; ++q) {               // 4 phases: C-quadrants
            const int mb = (q >> 1) * 4, nb2 = (q & 1) * 2;
            bf16x8 af[4][2], bfv[2][2];
            #pragma unroll
            for (int mi = 0; mi < 4; ++mi) {
                const int lr = (mb + mi) * 16 + lq;
                #pragma unroll
                for (int kk = 0; kk < 2; ++kk) {
                    const int g = kk * 4 + hk;
                    af[mi][kk] = *(const bf16x8*)(Ah + lr * 128 + ((g ^ (lr & 7)) << 4));
                }
            }
            #pragma unroll
            for (int nj = 0; nj < 2; ++nj) {
                const int lc = (wc & 1) * 64 + (nb2 + nj) * 16 + lq;
                #pragma unroll
                for (int kk = 0; kk < 2; ++kk) {
                    const int g = kk * 4 + hk;
                    bfv[nj][kk] = *(const bf16x8*)(Bh + lc * 128 + ((g ^ (lc & 7)) << 4));
                }
            }
            __builtin_amdgcn_s_setprio(1);
            #pragma unroll
            for (int mi = 0; mi < 4; ++mi)
                #pragma unroll
                for (int nj = 0; nj < 2; ++nj)
                    #pragma unroll
                    for (int kk = 0; kk < 2; ++kk)
                        acc[mb + mi][nb2 + nj] =
                            mfma16(af[mi][kk], bfv[nj][kk], acc[mb + mi][nb2 + nj]);
            __builtin_amdgcn_s_setprio(0);
        }

        asm volatile("" ::: "memory");
        __builtin_amdgcn_s_barrier();   // all 8 waves done reading buf d
        if (t + 2 < NT) STG(d, t + 2);  // refill freed buffer, fire-and-forget
    }
#undef STG

    // epilogue: wave (wr,wc) writes its 128x64 tile
    const int r0 = tm + wr * 128 + hk * 4;
    const int c0 = tn + wc * 64 + lq;
    if (EPI == 0) {
        #pragma unroll
        for (int i = 0; i < 8; ++i)
            #pragma unroll
            for (int j = 0; j < 4; ++j)
                #pragma unroll
                for (int r = 0; r < 4; ++r)
                    C[(size_t)(r0 + i * 16 + r) * N + (c0 + j * 16)] = (bf16)acc[i][j][r];
    } else {
        #pragma unroll
        for (int j = 0; j < 4; ++j) {
            const float bv = bias[c0 + j * 16];
            #pragma unroll
            for (int i = 0; i < 8; ++i)
                #pragma unroll
                for (int r = 0; r < 4; ++r) {
                    const float v = acc[i][j][r] + bv;
                    const float gl = 0.5f * v * (1.0f + erff(v * 0.70710678118654752f));
                    C[(size_t)(r0 + i * 16 + r) * N + (c0 + j * 16)] = (bf16)gl;
                }
        }
    }
}

// ---------------------------------------------------------------------------
// bf16 MFMA GEMM, 3-stage counted-vmcnt pipeline (r9, proven) — used for the
// N=1024 shapes (out-proj, FF2 split-K) where a 256-wide tile grid is too
// small. 128x128 tile, BK=32, 4 waves. XCD-chunk swizzle (T1).
// EPI: 1 = +bias +residual, fp32 out; 3 = split-K partial
// ---------------------------------------------------------------------------
template<int EPI>
__global__ __launch_bounds__(256, 3)
void gemm_bt_kernel(const bf16* __restrict__ A, const bf16* __restrict__ BT,
                    const float* __restrict__ bias, const float* __restrict__ res,
                    void* __restrict__ Cout, int M, int N, int K, int ld)
{
    __shared__ bf16 As[3][4096];   // [buf][128 m][32 k]
    __shared__ bf16 Bs[3][4096];
    const int nb = N >> 7;
    const int chunk = (int)gridDim.x >> 3;
    int idx = (blockIdx.x & 7) * chunk + (blockIdx.x >> 3);
    int ks = 0;
    if (EPI == 3) {
        const int tiles = (M >> 7) * nb;
        ks = idx / tiles;
        idx -= ks * tiles;
    }
    const int bm = idx / nb, bn = idx - bm * nb;
    const int tm = bm << 7, tn = bn << 7;
    const int tid = threadIdx.x;
    const int lane = tid & 63, wave = tid >> 6;
    const int wm = (wave >> 1) << 6, wn = (wave & 1) << 6;
    const int kofs = ks * K;   // column offset for split-K slice

    const bf16* ga = A  + (size_t)(tm + wave * 32 + (lane >> 2)) * ld + kofs + ((lane & 3) << 3);
    const bf16* gb = BT + (size_t)(tn + wave * 32 + (lane >> 2)) * ld + kofs + ((lane & 3) << 3);
    const size_t k16 = (size_t)16 * ld;

    f32x4 acc[4][4] = {};
    const int ro = (lane & 15) * 32 + ((lane >> 4) << 3);

#define GSTAGE(BUF, KO) do {                          \
        bf16* la_ = &As[BUF][wave * 1024];            \
        bf16* lb_ = &Bs[BUF][wave * 1024];            \
        GLDS16(ga + (KO),       la_);                 \
        GLDS16(ga + (KO) + k16, la_ + 512);           \
        GLDS16(gb + (KO),       lb_);                 \
        GLDS16(gb + (KO) + k16, lb_ + 512);           \
    } while (0)

    GSTAGE(0, 0);
    GSTAGE(1, 32);
    GSTAGE(2, 64);
    int cur = 0;
    for (int k0 = 0; k0 < K; k0 += 32) {
        if (k0 + 96 <= K)      asm volatile("s_waitcnt vmcnt(8)" ::: "memory");
        else if (k0 + 64 <= K) asm volatile("s_waitcnt vmcnt(4)" ::: "memory");
        else                   asm volatile("s_waitcnt vmcnt(0)" ::: "memory");
        __builtin_amdgcn_s_barrier();

        bf16x8 af[4], bfr[4];
        #pragma unroll
        for (int i = 0; i < 4; ++i) {
            af[i]  = *(const bf16x8*)(&As[cur][0] + (wm + i * 16) * 32 + ro);
            bfr[i] = *(const bf16x8*)(&Bs[cur][0] + (wn + i * 16) * 32 + ro);
        }
        #pragma unroll
        for (int i = 0; i < 4; ++i)
            #pragma unroll
            for (int j = 0; j < 4; ++j)
                acc[i][j] = mfma16(af[i], bfr[j], acc[i][j]);

        asm volatile("" ::: "memory");
        __builtin_amdgcn_s_barrier();
        asm volatile("" ::: "memory");
        if (k0 + 96 < K) GSTAGE(cur, k0 + 96);
        cur = (cur == 2) ? 0 : cur + 1;
    }
#undef GSTAGE

    const int r0 = tm + wm + ((lane >> 4) << 2);
    const int c0 = tn + wn + (lane & 15);
    if (EPI == 1) {
        float* C = (float*)Cout;
        #pragma unroll
        for (int j = 0; j < 4; ++j) {
            const float bv = bias[c0 + j * 16];
            #pragma unroll
            for (int i = 0; i < 4; ++i)
                #pragma unroll
                for (int r = 0; r < 4; ++r) {
                    const size_t idx2 = (size_t)(r0 + i * 16 + r) * N + (c0 + j * 16);
                    C[idx2] = acc[i][j][r] + bv + res[idx2];
                }
        }
    } else {   // EPI == 3: fp32 partial, slice ks
        float* C = (float*)(ks == 0 ? Cout : (void*)res);
        #pragma unroll
        for (int j = 0; j < 4; ++j)
            #pragma unroll
            for (int i = 0; i < 4; ++i)
                #pragma unroll
                for (int r = 0; r < 4; ++r)
                    C[(size_t)(r0 + i * 16 + r) * N + (c0 + j * 16)] = acc[i][j][r];
    }
}

// ---------------------------------------------------------------------------
// FF2 split-K reduce: out = p0 + p1 + bias + res  (all fp32, [NROWS][DIMM])
// ---------------------------------------------------------------------------
__global__ __launch_bounds__(256) void ff2_reduce_kernel(
    const float* __restrict__ p0, const float* __restrict__ p1,
    const float* __restrict__ bias, const float* __restrict__ res,
    float* __restrict__ out)
{
    const int i = blockIdx.x * 256 + threadIdx.x;    // float4 index
    const float4 a = ((const float4*)p0)[i];
    const float4 b = ((const float4*)p1)[i];
    const float4 r = ((const float4*)res)[i];
    const float4 g = ((const float4*)bias)[i & 255]; // DIMM/4 = 256 float4/row
    float4 o;
    o.x = a.x + b.x + r.x + g.x;
    o.y = a.y + b.y + r.y + g.y;
    o.z = a.z + b.z + r.z + g.z;
    o.w = a.w + b.w + r.w + g.w;
    ((float4*)out)[i] = o;
}

// ---------------------------------------------------------------------------
// V transpose per head: qkv[b][n][2*DIMM + h*64 + d] -> vT[bh][d][n]
// ---------------------------------------------------------------------------
__global__ __launch_bounds__(256) void vtrans_kernel(
    const bf16* __restrict__ qkv, bf16* __restrict__ vT)
{
    __shared__ bf16 t[64 * 64];
    const int n0 = blockIdx.x * 64;
    const int bh = blockIdx.y;
    const int b = bh >> 4, h = bh & 15;
    const bf16* src = qkv + (size_t)(b * SEQ + n0) * QKV3 + 2 * DIMM + h * DHEAD;

    #pragma unroll
    for (int it = 0; it < 2; ++it) {
        const int c = it * 256 + threadIdx.x;   // 512 chunks of 8 elems
        const int n = c >> 3, d8 = (c & 7) * 8;
        const bf16x8 v8 = *(const bf16x8*)(src + (size_t)n * QKV3 + d8);
        const int byte = (n * 128 + d8 * 2) ^ (((n >> 3) & 7) << 4);
        *(bf16x8*)((char*)t + byte) = v8;
    }
    __syncthreads();
    #pragma unroll
    for (int it = 0; it < 2; ++it) {
        const int c = it * 256 + threadIdx.x;
        const int d = c >> 3, nc = c & 7;
        bf16x8 o8;
        #pragma unroll
        for (int i = 0; i < 8; ++i) {
            const int n = nc * 8 + i;
            const int byte = (n * 128 + d * 2) ^ ((nc & 7) << 4);
            o8[i] = *(const bf16*)((const char*)t + byte);
        }
        *(bf16x8*)(vT + (size_t)bh * DHEAD * SEQ + (size_t)d * SEQ + n0 + nc * 8) = o8;
    }
}

// ---------------------------------------------------------------------------
// Flash attention v5 (r7-proven, 74 us) — unchanged.
// ---------------------------------------------------------------------------
__global__ __launch_bounds__(256, 4)
void attn_kernel(const bf16* __restrict__ qkv, const bf16* __restrict__ vT,
                 bf16* __restrict__ out)
{
    __shared__ bf16 Ks[2][64 * 64];
    __shared__ bf16 Vs[2][64 * 64];
    __shared__ bf16 Ps[4][16 * 64];
    const int bid = blockIdx.x;                    // 0..1023
    const int idx = (bid & 7) * 128 + (bid >> 3);  // bijective XCD swizzle
    const int qt = idx & 31;
    const int bh = idx >> 5;                       // 4 bh per XCD chunk
    const int b = bh >> 4, h = bh & 15;
    const int tid = threadIdx.x;
    const int lane = tid & 63, wave = tid >> 6;
    const int q = lane & 15, hi = lane >> 4;

    const bf16* qbase = qkv + (size_t)(b * SEQ) * QKV3 + h * DHEAD;
    const bf16* kbase = qbase + DIMM;
    const bf16* vbase = vT + (size_t)bh * DHEAD * SEQ;

    const int q0 = qt * 64 + wave * 16;
    bf16x8 qf[2];
    {
        const bf16* qp = qbase + (size_t)(q0 + q) * QKV3 + (hi << 3);
        qf[0] = *(const bf16x8*)qp;
        qf[1] = *(const bf16x8*)(qp + 32);
        #pragma unroll
        for (int j = 0; j < 8; ++j) {
            qf[0][j] = (bf16)((float)qf[0][j] * 0.125f);
            qf[1][j] = (bf16)((float)qf[1][j] * 0.125f);
        }
    }

    const int srow = lane >> 3;
    const int scol = ((lane & 7) ^ srow) << 3;
    const bf16* gk = kbase + (size_t)(wave * 16 + srow) * QKV3 + scol;
    const bf16* gv = vbase + (size_t)(wave * 16 + srow) * SEQ + scol;

#define STAGE(BUF, KT) do {                                        \
        bf16* lk_ = &Ks[BUF][wave * 1024];                         \
        bf16* lv_ = &Vs[BUF][wave * 1024];                         \
        GLDS16(gk + (size_t)(KT) * QKV3,       lk_);               \
        GLDS16(gk + (size_t)((KT) + 8) * QKV3, lk_ + 512);         \
        GLDS16(gv + (KT),                      lv_);               \
        GLDS16(gv + (KT) + 8 * SEQ,            lv_ + 512);         \
    } while (0)

    float m = -1e30f, l = 0.0f;
    f32x4 o[4] = {};

    STAGE(0, 0);
    int cur = 0;
    for (int kt = 0; kt < SEQ; kt += 64) {
        __syncthreads();
        if (kt + 64 < SEQ) STAGE(cur ^ 1, kt + 64);

        f32x4 sv[4];
        __builtin_amdgcn_s_setprio(1);
        #pragma unroll
        for (int kf = 0; kf < 4; ++kf) {
            f32x4 z = {0.f, 0.f, 0.f, 0.f};
            sv[kf] = z;
            #pragma unroll
            for (int ks = 0; ks < 2; ++ks) {
                const int row = kf * 16 + q;
                const int bo = (row * 128 + ks * 64 + (hi << 4)) ^ ((row & 7) << 4);
                const bf16x8 kfrag = *(const bf16x8*)((const char*)&Ks[cur][0] + bo);
                sv[kf] = mfma16(kfrag, qf[ks], sv[kf]);
            }
        }
        __builtin_amdgcn_s_setprio(0);

        float pmax;
        {
            float a = fmaxf(fmaxf(sv[0][0], sv[0][1]), fmaxf(sv[0][2], sv[0][3]));
            float b2 = fmaxf(fmaxf(sv[1][0], sv[1][1]), fmaxf(sv[1][2], sv[1][3]));
            float c = fmaxf(fmaxf(sv[2][0], sv[2][1]), fmaxf(sv[2][2], sv[2][3]));
            float d = fmaxf(fmaxf(sv[3][0], sv[3][1]), fmaxf(sv[3][2], sv[3][3]));
            pmax = fmaxf(fmaxf(a, b2), fmaxf(c, d));
        }
        pmax = fmaxf(pmax, __shfl_xor(pmax, 16, 64));
        pmax = fmaxf(pmax, __shfl_xor(pmax, 32, 64));

        if (__any(pmax - m > 8.0f)) {
            const float nm = fmaxf(m, pmax);
            const float fr = __expf(m - nm);
            l *= fr;
            #pragma unroll
            for (int df = 0; df < 4; ++df) {
                o[df][0] *= fr; o[df][1] *= fr;
                o[df][2] *= fr; o[df][3] *= fr;
            }
            m = nm;
        }

        float rsum = 0.0f;
        #pragma unroll
        for (int kf = 0; kf < 4; ++kf) {
            float p0 = __expf(sv[kf][0] - m);
            float p1 = __expf(sv[kf][1] - m);
            float p2 = __expf(sv[kf][2] - m);
            float p3 = __expf(sv[kf][3] - m);
            rsum += (p0 + p1) + (p2 + p3);
            bf16x4 pk = { (bf16)p0, (bf16)p1, (bf16)p2, (bf16)p3 };
            const int bo = (q * 128 + kf * 32 + hi * 8) ^ ((q & 7) << 4);
            *(bf16x4*)((char*)Ps[wave] + bo) = pk;
        }
        rsum += __shfl_xor(rsum, 16, 64);
        rsum += __shfl_xor(rsum, 32, 64);
        l += rsum;

        bf16x8 pf[2];
        #pragma unroll
        for (int ks = 0; ks < 2; ++ks) {
            const int bo = (q * 128 + ks * 64 + (hi << 4)) ^ ((q & 7) << 4);
            pf[ks] = *(const bf16x8*)((const char*)Ps[wave] + bo);
        }
        __builtin_amdgcn_s_setprio(1);
        #pragma unroll
        for (int df = 0; df < 4; ++df)
            #pragma unroll
            for (int ks = 0; ks < 2; ++ks) {
                const int rowv = df * 16 + q;
                const int bo = (rowv * 128 + ks * 64 + (hi << 4)) ^ ((rowv & 7) << 4);
                const bf16x8 vfrag = *(const bf16x8*)((const char*)&Vs[cur][0] + bo);
                o[df] = mfma16(vfrag, pf[ks], o[df]);
            }
        __builtin_amdgcn_s_setprio(0);
        cur ^= 1;
    }
#undef STAGE

    {
        const float inv = 1.0f / l;
        const int grow = b * SEQ + q0 + q;
        #pragma unroll
        for (int df = 0; df < 4; ++df) {
            bf16x4 pk = { (bf16)(o[df][0] * inv), (bf16)(o[df][1] * inv),
                          (bf16)(o[df][2] * inv), (bf16)(o[df][3] * inv) };
            *(bf16x4*)(out + (size_t)grow * DIMM + h * DHEAD + df * 16 + hi * 4) = pk;
        }
    }
}

// ---------------------------------------------------------------------------
extern "C" void kernel_launch(void* const* d_in, const int* in_sizes, int n_in,
                              void* d_out, int out_size, void* d_ws, size_t ws_size,
                              hipStream_t stream)
{
    (void)in_sizes; (void)n_in; (void)out_size;
    const float* x    = (const float*)d_in[0];
    const float* ln1g = (const float*)d_in[1];
    const float* ln1b = (const float*)d_in[2];
    const float* ln2g = (const float*)d_in[3];
    const float* ln2b = (const float*)d_in[4];
    const float* wqkv = (const float*)d_in[5];
    const float* wout = (const float*)d_in[6];
    const float* bout = (const float*)d_in[7];
    const float* wff1 = (const float*)d_in[8];
    const float* bff1 = (const float*)d_in[9];
    const float* wff2 = (const float*)d_in[10];
    const float* bff2 = (const float*)d_in[11];

    char* ws = (char*)d_ws;
    const dim3 blk(256);
    const dim3 blk512(512);
    const bool splitk = ws_size >= 92274688ULL;   // 88 MB packed layout

    if (splitk) {
        // Phase-lifetime-packed layout (all live ranges disjoint; 88 MB):
        bf16*  wff2T = (bf16*)(ws);
        bf16*  woutT = (bf16*)(ws + 8388608);
        bf16*  wff1T = (bf16*)(ws + 10485760);
        bf16*  wqkvT = (bf16*)(ws + 18874368);
        bf16*  hbuf  = (bf16*)(ws + 25165824);
        bf16*  qkvb  = (bf16*)(ws + 33554432);
        bf16*  vT    = (bf16*)(ws + 58720256);
        bf16*  attnb = (bf16*)(ws + 67108864);
        float* x2    = (float*)(ws + 75497472);
        bf16*  fbuf  = (bf16*)(ws + 41943040);
        float* p0    = (float*)(ws + 8388608);
        float* p1    = (float*)(ws + 25165824);

        tcast_kernel<<<dim3(QKV3 / 32, DIMM / 32), blk, 0, stream>>>(wqkv, wqkvT, DIMM, QKV3);
        tcast_kernel<<<dim3(DIMM / 32, DIMM / 32), blk, 0, stream>>>(wout, woutT, DIMM, DIMM);
        tcast_kernel<<<dim3(FFD  / 32, DIMM / 32), blk, 0, stream>>>(wff1, wff1T, DIMM, FFD);
        tcast_kernel<<<dim3(DIMM / 32, FFD  / 32), blk, 0, stream>>>(wff2, wff2T, FFD, DIMM);

        ln_cast_kernel<<<NROWS, blk, 0, stream>>>(x, ln1g, ln1b, hbuf);
        gemm256_kernel<0><<<(NROWS / 256) * (QKV3 / 256), blk512, 0, stream>>>(
            hbuf, wqkvT, nullptr, qkvb, NROWS, QKV3, DIMM, DIMM);
        vtrans_kernel<<<dim3(SEQ / 64, BATCH * NHEAD), blk, 0, stream>>>(qkvb, vT);
        attn_kernel<<<dim3(1024), blk, 0, stream>>>(qkvb, vT, attnb);
        gemm_bt_kernel<1><<<(NROWS / 128) * (DIMM / 128), blk, 0, stream>>>(
            attnb, woutT, bout, x, x2, NROWS, DIMM, DIMM, DIMM);
        ln_cast_kernel<<<NROWS, blk, 0, stream>>>(x2, ln2g, ln2b, hbuf);
        gemm256_kernel<2><<<(NROWS / 256) * (FFD / 256), blk512, 0, stream>>>(
            hbuf, wff1T, bff1, fbuf, NROWS, FFD, DIMM, DIMM);
        gemm_bt_kernel<3><<<2 * (NROWS / 128) * (DIMM / 128), blk, 0, stream>>>(
            fbuf, wff2T, nullptr, (const float*)p1, p0, NROWS, DIMM, FFD / 2, FFD);
        ff2_reduce_kernel<<<(NROWS * DIMM) / 1024, blk, 0, stream>>>(
            p0, p1, bff2, x2, (float*)d_out);
    } else {
        // Fallback: single-pass FF2, r4 layout.
        bf16*  wqkvT = (bf16*)(ws);
        bf16*  woutT = (bf16*)(ws + 6291456);
        bf16*  wff1T = (bf16*)(ws + 8388608);
        bf16*  wff2T = (bf16*)(ws + 16777216);
        float* x2    = (float*)(ws + 25165824);
        bf16*  vT    = (bf16*)(ws + 25165824);
        bf16*  hbuf  = (bf16*)(ws + 41943040);
        bf16*  qkvb  = (bf16*)(ws + 50331648);
        bf16*  attnb = (bf16*)(ws + 75497472);
        bf16*  fbuf  = (bf16*)(ws + 50331648);

        tcast_kernel<<<dim3(QKV3 / 32, DIMM / 32), blk, 0, stream>>>(wqkv, wqkvT, DIMM, QKV3);
        tcast_kernel<<<dim3(DIMM / 32, DIMM / 32), blk, 0, stream>>>(wout, woutT, DIMM, DIMM);
        tcast_kernel<<<dim3(FFD  / 32, DIMM / 32), blk, 0, stream>>>(wff1, wff1T, DIMM, FFD);
        tcast_kernel<<<dim3(DIMM / 32, FFD  / 32), blk, 0, stream>>>(wff2, wff2T, FFD, DIMM);

        ln_cast_kernel<<<NROWS, blk, 0, stream>>>(x, ln1g, ln1b, hbuf);
        gemm256_kernel<0><<<(NROWS / 256) * (QKV3 / 256), blk512, 0, stream>>>(
            hbuf, wqkvT, nullptr, qkvb, NROWS, QKV3, DIMM, DIMM);
        vtrans_kernel<<<dim3(SEQ / 64, BATCH * NHEAD), blk, 0, stream>>>(qkvb, vT);
        attn_kernel<<<dim3(1024), blk, 0, stream>>>(qkvb, vT, attnb);
        gemm_bt_kernel<1><<<(NROWS / 128) * (DIMM / 128), blk, 0, stream>>>(
            attnb, woutT, bout, x, x2, NROWS, DIMM, DIMM, DIMM);
        ln_cast_kernel<<<NROWS, blk, 0, stream>>>(x2, ln2g, ln2b, hbuf);
        gemm256_kernel<2><<<(NROWS / 256) * (FFD / 256), blk512, 0, stream>>>(
            hbuf, wff1T, bff1, fbuf, NROWS, FFD, DIMM, DIMM);
        gemm_bt_kernel<1><<<(NROWS / 128) * (DIMM / 128), blk, 0, stream>>>(
            fbuf, wff2T, bff2, x2, (float*)d_out, NROWS, DIMM, FFD, FFD);
    }
}